// Round 8
// baseline (131.075 us; speedup 1.0000x reference)
//
#include <hip/hip_runtime.h>
#include <math.h>

#define KNOTS 8
#define HIDN 32
#define TT 4096
#define CC 512
#define NB 32
#define BOUNDF 5.0f
#define CT 32            // channels per block
#define CL 16            // c-lanes (each owns a channel PAIR)
#define NTG 32           // t-rows covered per pass
#define TPT (TT / NTG)   // 128 float2 elements per thread
#define ROWS2 (CC / 2)   // 256 float2 per t-row

typedef float f32x2 __attribute__((ext_vector_type(2)));

// One block = one (batch, 32-channel) slice, 512 threads = 16 c-lanes x 32 t-rows.
// All global traffic is f32x2 (8B/lane). Phase 1: moments. Finalize: 32 lanes ->
// spline params in LDS (even/odd split arrays -> 2-way bank aliasing = free).
// Phase 2: re-read own slice in REVERSE t order (L3-hot), apply, NT stores.

__device__ __forceinline__ float rqs_one(float z,
    float k1, float k2, float k3, float k4, float k5, float k6, float k7,
    const f32x2* __restrict__ bZ, const f32x2* __restrict__ bY,
    const f32x2* __restrict__ bD, int lc)
{
    const bool  c4 = z >= k4;
    const float mB = c4 ? k6 : k2;
    const bool  cB = z >= mB;
    const float nLo = c4 ? k5 : k1;
    const float nHi = c4 ? k7 : k3;
    const float mC = cB ? nHi : nLo;
    const bool  cC = z >= mC;
    const int off = (c4 ? 4*CL : 0) + (cB ? 2*CL : 0) + (cC ? CL : 0) + lc;

    const f32x2 Z = bZ[off];
    const f32x2 Y = bY[off];
    const f32x2 D = bD[off];

    const float zeta = fmaf(z, Z.y, Z.x);
    const float u    = fmaf(-zeta, zeta, zeta);      // zeta*(1-zeta)
    const float s    = Y.y * Z.y;                    // h * invw
    const float R    = fmaf(-2.f, s, D.y);           // d0+d1-2s
    const float den  = fmaf(R, u, s);
    const float inner= fmaf(s * zeta, zeta, D.x * u);
    const float res  = fmaf(Y.y * inner,
                            __builtin_amdgcn_rcpf(fmaxf(den, 1e-8f)), Y.x);
    return (fabsf(z) > BOUNDF) ? z : res;
}

__global__ __launch_bounds__(512, 4)
void k_fused(const float* __restrict__ x, const float* __restrict__ W1,
             const float* __restrict__ b1, const float* __restrict__ W2,
             const float* __restrict__ b2, float* __restrict__ out)
{
    const int bb = blockIdx.y;               // 0..31
    const int c0 = blockIdx.x * CT;          // 0,32,...,480
    const int lc = threadIdx.x & (CL - 1);   // 0..15 (channel pair 2lc, 2lc+1)
    const int tg = threadIdx.x >> 4;         // 0..31 (t-row group)

    __shared__ f32x2 red2[NTG][4][CL];       // (even,odd) partial moments
    __shared__ float mom[4][CT];
    __shared__ float pA[CT], pB[CT];
    __shared__ float pKx[7][CT];
    __shared__ f32x2 bZe[KNOTS][CL], bZo[KNOTS][CL];   // (-kxl*invw, invw)
    __shared__ f32x2 bYe[KNOTS][CL], bYo[KNOTS][CL];   // (kyl, h)
    __shared__ f32x2 bDe[KNOTS][CL], bDo[KNOTS][CL];   // (d0, d0+d1)

    const size_t base2 = ((size_t)bb * TT * CC + c0) / 2 + lc + (size_t)tg * ROWS2;
    const f32x2* pxt = (const f32x2*)x + base2;

    // ---- Phase 1: raw moments, f32x2 loads (128 iters, stride 32 rows) ----
    float s1e = 0.f, s2e = 0.f, s3e = 0.f, s4e = 0.f;
    float s1o = 0.f, s2o = 0.f, s3o = 0.f, s4o = 0.f;
    #pragma unroll 8
    for (int k = 0; k < TPT; ++k) {
        const f32x2 v = pxt[(size_t)k * (NTG * ROWS2)];
        const float ve = v.x, vo = v.y;
        const float ve2 = ve * ve, vo2 = vo * vo;
        s1e += ve;                  s1o += vo;
        s2e = fmaf(ve,  ve,  s2e);  s2o = fmaf(vo,  vo,  s2o);
        s3e = fmaf(ve2, ve,  s3e);  s3o = fmaf(vo2, vo,  s3o);
        s4e = fmaf(ve2, ve2, s4e);  s4o = fmaf(vo2, vo2, s4o);
    }
    red2[tg][0][lc] = (f32x2){s1e, s1o};
    red2[tg][1][lc] = (f32x2){s2e, s2o};
    red2[tg][2][lc] = (f32x2){s3e, s3o};
    red2[tg][3][lc] = (f32x2){s4e, s4o};
    __syncthreads();

    if (threadIdx.x < 64) {
        const int m = threadIdx.x >> 4, c = threadIdx.x & (CL - 1);
        f32x2 acc = (f32x2){0.f, 0.f};
        #pragma unroll
        for (int g = 0; g < NTG; ++g) acc += red2[g][m][c];
        mom[m][2*c]   = acc.x;
        mom[m][2*c+1] = acc.y;
    }
    __syncthreads();

    // ---- Finalize: one lane per channel ----
    if (threadIdx.x < CT) {
        const int c = threadIdx.x;
        const float n  = (float)TT;
        const float t1 = mom[0][c], t2 = mom[1][c], t3 = mom[2][c], t4 = mom[3][c];
        const float mu  = t1 / n;
        const float ex2 = t2 / n, ex3 = t3 / n, ex4 = t4 / n;
        float var = (t2 - n * mu * mu) / (n - 1.f);
        var = fmaxf(var, 0.f);
        const float sig  = fmaxf(sqrtf(var), 1e-4f);
        const float inv  = 1.f / sig;
        const float mu2  = mu * mu;
        const float ez3  = ex3 - 3.f * mu * ex2 + 2.f * mu * mu2;
        const float ez4  = ex4 - 4.f * mu * ex3 + 6.f * mu2 * ex2 - 3.f * mu2 * mu2;
        const float inv2 = inv * inv;
        const float skew  = ez3 * inv2 * inv;
        const float ekurt = ez4 * inv2 * inv2 - 3.f;

        float hid[HIDN];
        #pragma unroll
        for (int h = 0; h < HIDN; ++h) {
            float v = fmaf(W1[2*h], skew, fmaf(W1[2*h+1], ekurt, b1[h]));
            hid[h] = fmaxf(v, 0.f);
        }

        float e[KNOTS], kxr[KNOTS+1], kyr[KNOTS+1], dr[KNOTS+1];
        {   // widths -> kx
            float mx = -1e30f;
            #pragma unroll
            for (int o = 0; o < KNOTS; ++o) {
                float acc = b2[o];
                #pragma unroll
                for (int h = 0; h < HIDN; ++h) acc = fmaf(W2[o*HIDN + h], hid[h], acc);
                e[o] = acc; mx = fmaxf(mx, acc);
            }
            float sum = 0.f;
            #pragma unroll
            for (int o = 0; o < KNOTS; ++o) { e[o] = expf(e[o] - mx); sum += e[o]; }
            const float scale = (2.f * BOUNDF) / sum;
            float cum = -BOUNDF; kxr[0] = -BOUNDF;
            #pragma unroll
            for (int o = 0; o < KNOTS; ++o) { cum = fmaf(e[o], scale, cum); kxr[o+1] = cum; }
        }
        {   // heights -> ky
            float mx = -1e30f;
            #pragma unroll
            for (int o = 0; o < KNOTS; ++o) {
                float acc = b2[KNOTS + o];
                #pragma unroll
                for (int h = 0; h < HIDN; ++h) acc = fmaf(W2[(KNOTS+o)*HIDN + h], hid[h], acc);
                e[o] = acc; mx = fmaxf(mx, acc);
            }
            float sum = 0.f;
            #pragma unroll
            for (int o = 0; o < KNOTS; ++o) { e[o] = expf(e[o] - mx); sum += e[o]; }
            const float scale = (2.f * BOUNDF) / sum;
            float cum = -BOUNDF; kyr[0] = -BOUNDF;
            #pragma unroll
            for (int o = 0; o < KNOTS; ++o) { cum = fmaf(e[o], scale, cum); kyr[o+1] = cum; }
        }
        #pragma unroll
        for (int o = 0; o < KNOTS+1; ++o) {  // derivs = softplus + 1e-3
            float acc = b2[2*KNOTS + o];
            #pragma unroll
            for (int h = 0; h < HIDN; ++h) acc = fmaf(W2[(2*KNOTS+o)*HIDN + h], hid[h], acc);
            float sp = fmaxf(acc, 0.f) + log1pf(expf(-fabsf(acc)));
            dr[o] = sp + 1e-3f;
        }

        pA[c] = inv;
        pB[c] = -mu * inv;
        #pragma unroll
        for (int j = 1; j <= 7; ++j) pKx[j-1][c] = kxr[j];

        const int  ch = c >> 1;
        const bool odd = (c & 1) != 0;
        #pragma unroll
        for (int j = 0; j < KNOTS; ++j) {
            const float w    = kxr[j+1] - kxr[j];
            const float wm   = fmaxf(w, 1e-8f);
            const float invw = 1.f / wm;
            const float h    = kyr[j+1] - kyr[j];
            const f32x2 Z = {-kxr[j] * invw, invw};
            const f32x2 Y = {kyr[j], h};
            const f32x2 D = {dr[j], dr[j] + dr[j+1]};
            if (odd) { bZo[j][ch] = Z; bYo[j][ch] = Y; bDo[j][ch] = D; }
            else     { bZe[j][ch] = Z; bYe[j][ch] = Y; bDe[j][ch] = D; }
        }
    }
    __syncthreads();

    // ---- Phase 2: re-read slice in REVERSE t order, apply spline ----
    const float aE = pA[2*lc],   aO = pA[2*lc+1];
    const float bE = pB[2*lc],   bO = pB[2*lc+1];
    const float e1 = pKx[0][2*lc], e2 = pKx[1][2*lc], e3 = pKx[2][2*lc],
                e4 = pKx[3][2*lc], e5 = pKx[4][2*lc], e6 = pKx[5][2*lc],
                e7 = pKx[6][2*lc];
    const float o1 = pKx[0][2*lc+1], o2 = pKx[1][2*lc+1], o3 = pKx[2][2*lc+1],
                o4 = pKx[3][2*lc+1], o5 = pKx[4][2*lc+1], o6 = pKx[5][2*lc+1],
                o7 = pKx[6][2*lc+1];
    f32x2* pot = (f32x2*)out + base2;

    for (int kb = TPT / 8 - 1; kb >= 0; --kb) {   // 15..0 (reverse)
        f32x2 xv[8];
        #pragma unroll
        for (int j = 0; j < 8; ++j)
            xv[j] = pxt[(size_t)(kb * 8 + j) * (NTG * ROWS2)];
        #pragma unroll
        for (int j = 0; j < 8; ++j) {
            const float zE = fmaf(xv[j].x, aE, bE);
            const float zO = fmaf(xv[j].y, aO, bO);
            const float rE = rqs_one(zE, e1,e2,e3,e4,e5,e6,e7,
                                     &bZe[0][0], &bYe[0][0], &bDe[0][0], lc);
            const float rO = rqs_one(zO, o1,o2,o3,o4,o5,o6,o7,
                                     &bZo[0][0], &bYo[0][0], &bDo[0][0], lc);
            const f32x2 r = {rE, rO};
            __builtin_nontemporal_store(r, &pot[(size_t)(kb * 8 + j) * (NTG * ROWS2)]);
        }
    }
}

extern "C" void kernel_launch(void* const* d_in, const int* in_sizes, int n_in,
                              void* d_out, int out_size, void* d_ws, size_t ws_size,
                              hipStream_t stream) {
    const float* x  = (const float*)d_in[0];
    const float* W1 = (const float*)d_in[1];
    const float* b1 = (const float*)d_in[2];
    const float* W2 = (const float*)d_in[3];
    const float* b2 = (const float*)d_in[4];
    float* out = (float*)d_out;

    k_fused<<<dim3(CC / CT, NB), dim3(512), 0, stream>>>(x, W1, b1, W2, b2, out);
}